// Round 1
// baseline (65.851 us; speedup 1.0000x reference)
//
#include <hip/hip_runtime.h>
#include <math.h>

#define NUM_C   1000
#define MOM     0.9f
#define EPS     1e-6f

// ---------------- kernel 1: per-row CE + per-class atomic sums ----------------
// One wave (64 lanes) per row. 250 float4 per row (1000 fp32). Each lane loads
// up to 4 float4 (coalesced 1 KiB per wave per step), keeps them in registers,
// wave-reduces max then sum(exp(x-m)).
__global__ __launch_bounds__(256) void ce_kernel(const float* __restrict__ logits,
                                                 const int*   __restrict__ targets,
                                                 float* __restrict__ ce,
                                                 float* __restrict__ sums,
                                                 float* __restrict__ counts,
                                                 int n) {
    const int wave = threadIdx.x >> 6;
    const int lane = threadIdx.x & 63;
    const int row  = blockIdx.x * 4 + wave;
    if (row >= n) return;

    const float4* rp = reinterpret_cast<const float4*>(logits + (size_t)row * NUM_C);

    float4 v[4];
    float m = -INFINITY;
#pragma unroll
    for (int j = 0; j < 4; ++j) {
        int idx = j * 64 + lane;
        if (idx < 250) {
            v[j] = rp[idx];
            m = fmaxf(m, fmaxf(fmaxf(v[j].x, v[j].y), fmaxf(v[j].z, v[j].w)));
        } else {
            v[j] = make_float4(0.f, 0.f, 0.f, 0.f);
        }
    }
    // wave-wide max reduce (64 lanes)
#pragma unroll
    for (int off = 32; off > 0; off >>= 1)
        m = fmaxf(m, __shfl_xor(m, off, 64));

    float s = 0.f;
#pragma unroll
    for (int j = 0; j < 4; ++j) {
        int idx = j * 64 + lane;
        if (idx < 250) {
            s += expf(v[j].x - m);
            s += expf(v[j].y - m);
            s += expf(v[j].z - m);
            s += expf(v[j].w - m);
        }
    }
#pragma unroll
    for (int off = 32; off > 0; off >>= 1)
        s += __shfl_xor(s, off, 64);

    if (lane == 0) {
        int t = targets[row];
        float lt = logits[(size_t)row * NUM_C + t];
        float c = (m + logf(s)) - lt;   // -log_softmax at target
        ce[row] = c;
        atomicAdd(&sums[t], c);
        atomicAdd(&counts[t], 1.0f);
    }
}

// ---------------- kernel 2: EMA update of grad magnitudes ----------------
__global__ void gm_kernel(const float* __restrict__ gm_in,
                          const float* __restrict__ sums,
                          const float* __restrict__ counts,
                          float* __restrict__ new_gm) {
    int c = blockIdx.x * blockDim.x + threadIdx.x;
    if (c < NUM_C) {
        float cnt = counts[c];
        float g = gm_in[c];
        if (cnt > 0.f) {
            float cm = fabsf(sums[c] / fmaxf(cnt, 1.0f));
            g = MOM * g + (1.0f - MOM) * cm;
        }
        new_gm[c] = g;
    }
}

// ---------------- kernel 3: weighted sums ----------------
// out = sum(w*ce)/sum(w),  w[i] = 1/(new_gm[t[i]] + eps)
__global__ __launch_bounds__(256) void weight_kernel(const int*   __restrict__ targets,
                                                     const float* __restrict__ ce,
                                                     const float* __restrict__ new_gm,
                                                     float* __restrict__ accum,
                                                     int n) {
    float sw = 0.f, swc = 0.f;
    for (int i = blockIdx.x * blockDim.x + threadIdx.x; i < n;
         i += gridDim.x * blockDim.x) {
        int t = targets[i];
        float w = 1.0f / (new_gm[t] + EPS);
        sw  += w;
        swc += w * ce[i];
    }
#pragma unroll
    for (int off = 32; off > 0; off >>= 1) {
        sw  += __shfl_xor(sw,  off, 64);
        swc += __shfl_xor(swc, off, 64);
    }
    __shared__ float ssw[4], sswc[4];
    const int lane = threadIdx.x & 63;
    const int wave = threadIdx.x >> 6;
    if (lane == 0) { ssw[wave] = sw; sswc[wave] = swc; }
    __syncthreads();
    if (threadIdx.x == 0) {
        float a = 0.f, b = 0.f;
        for (int w2 = 0; w2 < 4; ++w2) { a += ssw[w2]; b += sswc[w2]; }
        atomicAdd(&accum[0], a);
        atomicAdd(&accum[1], b);
    }
}

// ---------------- kernel 4: final scalar ----------------
__global__ void final_kernel(const float* __restrict__ accum, float* __restrict__ out) {
    if (threadIdx.x == 0) out[0] = accum[1] / accum[0];
}

extern "C" void kernel_launch(void* const* d_in, const int* in_sizes, int n_in,
                              void* d_out, int out_size, void* d_ws, size_t ws_size,
                              hipStream_t stream) {
    const float* logits  = (const float*)d_in[0];
    const int*   targets = (const int*)d_in[1];
    const float* gm      = (const float*)d_in[2];
    float* out = (float*)d_out;

    const int n = in_sizes[1];  // number of rows / targets

    char* ws = (char*)d_ws;
    float* ce     = (float*)ws;                       // n floats
    float* sums   = (float*)(ws + (size_t)n * 4);     // NUM_C
    float* counts = sums + NUM_C;                     // NUM_C
    float* new_gm = counts + NUM_C;                   // NUM_C
    float* accum  = new_gm + NUM_C;                   // 2

    // zero the accumulated regions (sums, counts, [new_gm], accum) every call
    hipMemsetAsync(sums, 0, (3 * NUM_C + 2) * sizeof(float), stream);

    ce_kernel<<<(n + 3) / 4, 256, 0, stream>>>(logits, targets, ce, sums, counts, n);
    gm_kernel<<<(NUM_C + 255) / 256, 256, 0, stream>>>(gm, sums, counts, new_gm);
    weight_kernel<<<256, 256, 0, stream>>>(targets, ce, new_gm, accum, n);
    final_kernel<<<1, 64, 0, stream>>>(accum, out);
}

// Round 2
// 52.841 us; speedup vs baseline: 1.2462x; 1.2462x over previous
//
#include <hip/hip_runtime.h>
#include <math.h>

#define NUM_C   1000
#define MOM     0.9f
#define EPS     1e-6f

// ---------------- kernel 1: per-row CE + per-class atomic sums ----------------
// One wave (64 lanes) per row, 4 waves per 256-thread block. 250 float4 per
// row; each lane holds up to 4 float4 in registers (coalesced 1 KiB per wave
// per step). Wave-reduce max, then wave-reduce {sum(exp(x-m)), logit_at_target}
// in one butterfly. No second pass over logits, no ce[] materialization.
__global__ __launch_bounds__(256) void ce_kernel(const float* __restrict__ logits,
                                                 const int*   __restrict__ targets,
                                                 float* __restrict__ sums,
                                                 float* __restrict__ counts,
                                                 int n) {
    const int wave = threadIdx.x >> 6;
    const int lane = threadIdx.x & 63;
    const int row  = blockIdx.x * 4 + wave;
    if (row >= n) return;

    const int t  = targets[row];        // wave-uniform address -> one line
    const int tq = t >> 2;              // float4 index holding the target
    const int tc = t & 3;

    const float4* rp = reinterpret_cast<const float4*>(logits + (size_t)row * NUM_C);

    float4 v[4];
    float m = -INFINITY;
#pragma unroll
    for (int j = 0; j < 4; ++j) {
        int idx = j * 64 + lane;
        if (idx < 250) {
            v[j] = rp[idx];
            m = fmaxf(m, fmaxf(fmaxf(v[j].x, v[j].y), fmaxf(v[j].z, v[j].w)));
        }
    }
#pragma unroll
    for (int off = 32; off > 0; off >>= 1)
        m = fmaxf(m, __shfl_xor(m, off, 64));

    float s = 0.f;     // sum of exp(x - m)
    float lt = 0.f;    // logit at target (only the owning lane contributes)
#pragma unroll
    for (int j = 0; j < 4; ++j) {
        int idx = j * 64 + lane;
        if (idx < 250) {
            s += __expf(v[j].x - m);
            s += __expf(v[j].y - m);
            s += __expf(v[j].z - m);
            s += __expf(v[j].w - m);
            if (idx == tq) {
                float c = (tc == 0) ? v[j].x : (tc == 1) ? v[j].y
                        : (tc == 2) ? v[j].z : v[j].w;
                lt = c;
            }
        }
    }
#pragma unroll
    for (int off = 32; off > 0; off >>= 1) {
        s  += __shfl_xor(s,  off, 64);
        lt += __shfl_xor(lt, off, 64);
    }

    if (lane == 0) {
        float ce = (m + __logf(s)) - lt;   // -log_softmax at target
        atomicAdd(&sums[t], ce);
        atomicAdd(&counts[t], 1.0f);
    }
}

// ---------------- kernel 2: EMA + weighted ratio, fused ----------------
// out = [sum_c sums_c * w_c] / [sum_c cnt_c * w_c],  w_c = 1/(new_gm_c + eps)
// One block of 1024 threads covers all 1000 classes; block reduce; no atomics.
__global__ __launch_bounds__(1024) void finalize_kernel(const float* __restrict__ gm_in,
                                                        const float* __restrict__ sums,
                                                        const float* __restrict__ counts,
                                                        float* __restrict__ out) {
    const int c = threadIdx.x;
    float a = 0.f, b = 0.f;
    if (c < NUM_C) {
        float cnt = counts[c];
        float s   = sums[c];
        float g   = gm_in[c];
        if (cnt > 0.f) {
            float cm = fabsf(s / fmaxf(cnt, 1.0f));
            g = MOM * g + (1.0f - MOM) * cm;
        }
        float w = 1.0f / (g + EPS);
        a = cnt * w;   // sum of per-sample weights in this class
        b = s * w;     // sum of w * ce in this class
    }
#pragma unroll
    for (int off = 32; off > 0; off >>= 1) {
        a += __shfl_xor(a, off, 64);
        b += __shfl_xor(b, off, 64);
    }
    __shared__ float sa[16], sb[16];
    const int lane = threadIdx.x & 63;
    const int wv   = threadIdx.x >> 6;
    if (lane == 0) { sa[wv] = a; sb[wv] = b; }
    __syncthreads();
    if (threadIdx.x == 0) {
        float A = 0.f, B = 0.f;
        for (int i = 0; i < 16; ++i) { A += sa[i]; B += sb[i]; }
        out[0] = B / A;
    }
}

extern "C" void kernel_launch(void* const* d_in, const int* in_sizes, int n_in,
                              void* d_out, int out_size, void* d_ws, size_t ws_size,
                              hipStream_t stream) {
    const float* logits  = (const float*)d_in[0];
    const int*   targets = (const int*)d_in[1];
    const float* gm      = (const float*)d_in[2];
    float* out = (float*)d_out;

    const int n = in_sizes[1];  // number of rows / targets

    float* sums   = (float*)d_ws;       // NUM_C
    float* counts = sums + NUM_C;       // NUM_C

    hipMemsetAsync(sums, 0, 2 * NUM_C * sizeof(float), stream);

    ce_kernel<<<(n + 3) / 4, 256, 0, stream>>>(logits, targets, sums, counts, n);
    finalize_kernel<<<1, 1024, 0, stream>>>(gm, sums, counts, out);
}